// Round 1
// baseline (438.827 us; speedup 1.0000x reference)
//
#include <hip/hip_runtime.h>
#include <hip/hip_bf16.h>

#define DD 256
#define NGN 80000
#define NMN 20000
#define NEE 160000

typedef unsigned short u16;
typedef __attribute__((ext_vector_type(8))) short s16x8;
typedef __attribute__((ext_vector_type(4))) short s16x4;
typedef __attribute__((ext_vector_type(4))) float f32x4;

__device__ __forceinline__ u16 f2bf(float f) {
  union { float f; unsigned u; } v; v.f = f;
  unsigned r = (v.u + 0x7FFFu + ((v.u >> 16) & 1u)) >> 16;
  return (u16)r;
}

// Pack fp32 weight [K][256] -> bf16 fragment-linear layout [kt][nt][lane][8]
// slot->k bijection: k = kt*32 + 4*(lane>>4) + (i<4 ? i : 12+i); n = nt*16 + (lane&15)
__global__ void pack_weights(const float* __restrict__ W, u16* __restrict__ dst, int K) {
  int idx = blockIdx.x * 256 + threadIdx.x;
  if (idx >= K * 256) return;
  int i = idx & 7;
  int lane = (idx >> 3) & 63;
  int nt = (idx >> 9) & 15;
  int kt = idx >> 13;
  int k = kt * 32 + 4 * (lane >> 4) + (i < 4 ? i : 12 + i);
  int n = nt * 16 + (lane & 15);
  dst[idx] = f2bf(W[(size_t)k * 256 + n]);
}

__device__ __forceinline__ void stage16k(const u16* __restrict__ gsrc, u16* lds, int tid) {
  const s16x8* s = (const s16x8*)gsrc;
  s16x8* d = (s16x8*)lds;
#pragma unroll
  for (int j = 0; j < 4; ++j) d[tid + 256 * j] = s[tid + 256 * j];
}

// MODE 0: edge MLP (concat[efeat|grid[src]|mesh[dst]], K1=768) -> atomic scatter to agg
// MODE 1: src/grid MLP (K1=256) -> residual write
// MODE 2: dst/mesh MLP (concat[agg|mesh], K1=512) -> residual write
template <int MODE, int K1>
__global__ __launch_bounds__(256, 2) void mlp_fused(
    const float* __restrict__ xa, const float* __restrict__ xb,
    const float* __restrict__ xc,
    const int* __restrict__ sidx, const int* __restrict__ didx,
    const u16* __restrict__ W1p, const float* __restrict__ b1,
    const u16* __restrict__ W2p, const float* __restrict__ b2,
    const float* __restrict__ gam, const float* __restrict__ bet,
    const float* __restrict__ resid, float* __restrict__ out, int nrows) {
  __shared__ u16 bstage[8192];       // 16 KB weight k-slab
  __shared__ u16 hbuf[64 * 256];     // 32 KB hidden (bf16, XOR-swizzled rows)
  __shared__ float2 pstats[64][2];   // LN partial sums per row per col-half

  const int tid = threadIdx.x;
  const int lane = tid & 63;
  const int wave = tid >> 6;
  const int mr = wave >> 1, nc = wave & 1;
  const int g = lane >> 4, lr = lane & 15;
  const int row0 = blockIdx.x * 64;

  const float* pA[2][3];
#pragma unroll
  for (int mt = 0; mt < 2; ++mt) {
    int r = row0 + mr * 32 + mt * 16 + lr;
    if (MODE == 2) r = min(r, nrows - 1);
    pA[mt][0] = xa + (size_t)r * DD;
    if constexpr (MODE == 0) {
      pA[mt][1] = xb + (size_t)sidx[r] * DD;
      pA[mt][2] = xc + (size_t)didx[r] * DD;
    } else if constexpr (MODE == 2) {
      pA[mt][1] = xb + (size_t)r * DD;
    }
  }

  const f32x4 fz = {0.f, 0.f, 0.f, 0.f};
  f32x4 acc[2][8];
#pragma unroll
  for (int mt = 0; mt < 2; ++mt)
#pragma unroll
    for (int nt = 0; nt < 8; ++nt) acc[mt][nt] = fz;

  // ---------------- GEMM1: X @ W1 ----------------
#pragma unroll
  for (int region = 0; region < K1 / 256; ++region) {
    for (int kl = 0; kl < 8; ++kl) {
      const int kt = region * 8 + kl;
      __syncthreads();
      stage16k(W1p + (size_t)kt * 8192, bstage, tid);
      __syncthreads();
      s16x8 afr[2];
      const int c0 = kl * 32 + 4 * g;
#pragma unroll
      for (int mt = 0; mt < 2; ++mt) {
        const float* p = pA[mt][region] + c0;
        f32x4 f0 = *(const f32x4*)p;
        f32x4 f1 = *(const f32x4*)(p + 16);
        s16x8 a;
#pragma unroll
        for (int j = 0; j < 4; ++j) {
          a[j] = (short)f2bf(f0[j]);
          a[4 + j] = (short)f2bf(f1[j]);
        }
        afr[mt] = a;
      }
#pragma unroll
      for (int nt = 0; nt < 8; ++nt) {
        s16x8 b = *(const s16x8*)(bstage + ((size_t)(nc * 8 + nt) * 64 + lane) * 8);
        acc[0][nt] = __builtin_amdgcn_mfma_f32_16x16x32_bf16(afr[0], b, acc[0][nt], 0, 0, 0);
        acc[1][nt] = __builtin_amdgcn_mfma_f32_16x16x32_bf16(afr[1], b, acc[1][nt], 0, 0, 0);
      }
    }
  }

  // ---------------- bias1 + SiLU -> h (bf16, LDS, swizzled) ----------------
  {
    float b1v[8];
#pragma unroll
    for (int nt = 0; nt < 8; ++nt) b1v[nt] = b1[nc * 128 + nt * 16 + lr];
#pragma unroll
    for (int mt = 0; mt < 2; ++mt)
#pragma unroll
      for (int nt = 0; nt < 8; ++nt)
#pragma unroll
        for (int i = 0; i < 4; ++i) {
          float x = acc[mt][nt][i] + b1v[nt];
          float h = x / (1.f + __expf(-x));
          int rowL = mr * 32 + mt * 16 + 4 * g + i;
          int col = nc * 128 + nt * 16 + lr;
          int byte = rowL * 512 + ((col * 2) ^ ((rowL & 7) << 4));
          *(u16*)((char*)hbuf + byte) = f2bf(h);
        }
  }

  // ---------------- GEMM2: h @ W2 ----------------
  f32x4 acc2[2][8];
#pragma unroll
  for (int mt = 0; mt < 2; ++mt)
#pragma unroll
    for (int nt = 0; nt < 8; ++nt) acc2[mt][nt] = fz;

  for (int kt2 = 0; kt2 < 8; ++kt2) {
    __syncthreads();
    stage16k(W2p + (size_t)kt2 * 8192, bstage, tid);
    __syncthreads();
    s16x8 afr[2];
#pragma unroll
    for (int mt = 0; mt < 2; ++mt) {
      int rowL = mr * 32 + mt * 16 + lr;
      int swz = (rowL & 7) << 4;
      int cL = kt2 * 32 + 4 * g;
      s16x4 lo = *(const s16x4*)((char*)hbuf + rowL * 512 + ((cL * 2) ^ swz));
      s16x4 hi = *(const s16x4*)((char*)hbuf + rowL * 512 + (((cL + 16) * 2) ^ swz));
      s16x8 a;
#pragma unroll
      for (int j = 0; j < 4; ++j) {
        a[j] = lo[j];
        a[4 + j] = hi[j];
      }
      afr[mt] = a;
    }
#pragma unroll
    for (int nt = 0; nt < 8; ++nt) {
      s16x8 b = *(const s16x8*)(bstage + ((size_t)(nc * 8 + nt) * 64 + lane) * 8);
      acc2[0][nt] = __builtin_amdgcn_mfma_f32_16x16x32_bf16(afr[0], b, acc2[0][nt], 0, 0, 0);
      acc2[1][nt] = __builtin_amdgcn_mfma_f32_16x16x32_bf16(afr[1], b, acc2[1][nt], 0, 0, 0);
    }
  }

  // ---------------- bias2 + LayerNorm + (residual write | atomic scatter) ----------------
  float b2v[8], gv[8], bv[8];
#pragma unroll
  for (int nt = 0; nt < 8; ++nt) {
    int col = nc * 128 + nt * 16 + lr;
    b2v[nt] = b2[col];
    gv[nt] = gam[col];
    bv[nt] = bet[col];
  }
#pragma unroll
  for (int mt = 0; mt < 2; ++mt)
#pragma unroll
    for (int i = 0; i < 4; ++i) {
      float s = 0.f, s2 = 0.f;
#pragma unroll
      for (int nt = 0; nt < 8; ++nt) {
        float y = acc2[mt][nt][i] + b2v[nt];
        s += y;
        s2 += y * y;
      }
#pragma unroll
      for (int m = 1; m < 16; m <<= 1) {
        s += __shfl_xor(s, m);
        s2 += __shfl_xor(s2, m);
      }
      if (lr == 0) pstats[mr * 32 + mt * 16 + 4 * g + i][nc] = make_float2(s, s2);
    }
  __syncthreads();
#pragma unroll
  for (int mt = 0; mt < 2; ++mt)
#pragma unroll
    for (int i = 0; i < 4; ++i) {
      int rowL = mr * 32 + mt * 16 + 4 * g + i;
      float2 pa = pstats[rowL][0], pb = pstats[rowL][1];
      float sum = pa.x + pb.x, sq = pa.y + pb.y;
      float mu = sum * (1.f / 256.f);
      float var = fmaxf(sq * (1.f / 256.f) - mu * mu, 0.f);
      float rs = rsqrtf(var + 1e-5f);
      int rg = row0 + rowL;
      if (MODE == 2 && rg >= nrows) continue;
      int dn = 0;
      if constexpr (MODE == 0) dn = didx[rg];
#pragma unroll
      for (int nt = 0; nt < 8; ++nt) {
        int col = nc * 128 + nt * 16 + lr;
        float y = acc2[mt][nt][i] + b2v[nt];
        float val = (y - mu) * rs * gv[nt] + bv[nt];
        if constexpr (MODE == 0) {
          atomicAdd(out + (size_t)dn * DD + col, val);
        } else {
          out[(size_t)rg * DD + col] = resid[(size_t)rg * DD + col] + val;
        }
      }
    }
}

extern "C" void kernel_launch(void* const* d_in, const int* in_sizes, int n_in,
                              void* d_out, int out_size, void* d_ws, size_t ws_size,
                              hipStream_t stream) {
  const float* g2m  = (const float*)d_in[0];
  const float* grid = (const float*)d_in[1];
  const float* mesh = (const float*)d_in[2];
  const int* sidx = (const int*)d_in[3];
  const int* didx = (const int*)d_in[4];
  const float* eW1 = (const float*)d_in[5];
  const float* eb1 = (const float*)d_in[6];
  const float* eW2 = (const float*)d_in[7];
  const float* eb2 = (const float*)d_in[8];
  const float* eg  = (const float*)d_in[9];
  const float* ebt = (const float*)d_in[10];
  const float* sW1 = (const float*)d_in[11];
  const float* sb1 = (const float*)d_in[12];
  const float* sW2 = (const float*)d_in[13];
  const float* sb2 = (const float*)d_in[14];
  const float* sg  = (const float*)d_in[15];
  const float* sbt = (const float*)d_in[16];
  const float* dW1 = (const float*)d_in[17];
  const float* db1 = (const float*)d_in[18];
  const float* dW2 = (const float*)d_in[19];
  const float* db2 = (const float*)d_in[20];
  const float* dg  = (const float*)d_in[21];
  const float* dbt = (const float*)d_in[22];

  float* agg = (float*)d_ws;  // [NMN][256] fp32
  u16* wp = (u16*)((char*)d_ws + (size_t)NMN * DD * 4);
  u16* eW1p = wp;
  u16* eW2p = eW1p + 768 * 256;
  u16* sW1p = eW2p + 256 * 256;
  u16* sW2p = sW1p + 256 * 256;
  u16* dW1p = sW2p + 256 * 256;
  u16* dW2p = dW1p + 512 * 256;

  (void)hipMemsetAsync(agg, 0, (size_t)NMN * DD * 4, stream);
  pack_weights<<<768, 256, 0, stream>>>(eW1, eW1p, 768);
  pack_weights<<<256, 256, 0, stream>>>(eW2, eW2p, 256);
  pack_weights<<<256, 256, 0, stream>>>(sW1, sW1p, 256);
  pack_weights<<<256, 256, 0, stream>>>(sW2, sW2p, 256);
  pack_weights<<<512, 256, 0, stream>>>(dW1, dW1p, 512);
  pack_weights<<<256, 256, 0, stream>>>(dW2, dW2p, 256);

  float* gout = (float*)d_out;
  float* mout = gout + (size_t)NGN * DD;

  mlp_fused<0, 768><<<NEE / 64, 256, 0, stream>>>(
      g2m, grid, mesh, sidx, didx, eW1p, eb1, eW2p, eb2, eg, ebt, nullptr, agg, NEE);
  mlp_fused<1, 256><<<NGN / 64, 256, 0, stream>>>(
      grid, nullptr, nullptr, nullptr, nullptr, sW1p, sb1, sW2p, sb2, sg, sbt, grid, gout, NGN);
  mlp_fused<2, 512><<<(NMN + 63) / 64, 256, 0, stream>>>(
      agg, mesh, nullptr, nullptr, nullptr, dW1p, db1, dW2p, db2, dg, dbt, mesh, mout, NMN);
}